// Round 16
// baseline (54.018 us; speedup 1.0000x reference)
//
#include <hip/hip_runtime.h>
#include <math.h>

#define T_DIM 2048
#define B_DIM 4
#define BT (B_DIM * T_DIM)
#define MODEL 512
#define OUTF 256
#define WSZ 16
#define WIN 33

#define BM 128
#define BN 64
#define BK 32

#define TB 16    // t-rows per attn block (2 rows per wave, 8 waves)
#define HALO 48  // staged window rows (TB + 32)
#define TS 72    // padded k-stride for EwT/Ab (144B = 16B-aligned, ~2-way banks)

// 2*log2(e): GEMM epilogues store E = 2^(ESCALE*z) so attn needs no exp.
#define ESCALE 2.885390081777927f
#define ECLAMP 30.0f

typedef __attribute__((ext_vector_type(8))) short bf16x8;
typedef __attribute__((ext_vector_type(4))) float f32x4;

__device__ inline unsigned short f2bf(float f) {
  unsigned int u = __float_as_uint(f);
  u += 0x7fffu + ((u >> 16) & 1u);  // RNE
  return (unsigned short)(u >> 16);
}
__device__ inline float bflo(unsigned int u) {
  return __uint_as_float(u << 16);
}
__device__ inline float bfhi(unsigned int u) {
  return __uint_as_float(u & 0xffff0000u);
}
__device__ inline float fast_sigmoid(float z) {
  return __builtin_amdgcn_rcpf(1.f + __expf(-z));
}

// ---- micro-prep: W [768][256] f32 -> WT [256][768] bf16 (both weights) ----
__global__ __launch_bounds__(256) void prepW_kernel(
    const float* __restrict__ W_attn, const float* __restrict__ W_lin,
    unsigned short* __restrict__ wtT, unsigned short* __restrict__ wlT) {
  const int bid = blockIdx.x, o = threadIdx.x;
  const float* W = (bid < 96) ? W_attn : W_lin;
  unsigned short* WT = (bid < 96) ? wtT : wlT;
  const int k0 = ((bid < 96) ? bid : bid - 96) * 8;
  unsigned short t[8];
#pragma unroll
  for (int j = 0; j < 8; ++j) t[j] = f2bf(W[(k0 + j) * OUTF + o]);
  *(uint4*)&WT[o * 768 + k0] = *(const uint4*)t;
}

// ---- m97-style GEMM body: BM=128 x BN=64 x BK=32, 8 waves, dbuf LDS,
// 2-deep register prefetch, f32->bf16 cvt inside staging.
// MODE 0: x@[Wh|Wl1]: cb<4 -> ewe-domain bf16 (+b_attn), cb>=4 -> z1 f32.
// MODE 1: cb<4: enc@We -> E-domain bf16; cb>=4: enc@Wl2 -> plain bf16.
template <int KS, int MODE>
__device__ __forceinline__ void gemm_body(
    unsigned short (*As)[BM * 40], unsigned short (*Bs)[BN * 40], int rb,
    const float* __restrict__ A, int lda,
    const unsigned short* __restrict__ wtT,
    const unsigned short* __restrict__ wlT,
    const float* __restrict__ b_attn, const float* __restrict__ b_lin,
    unsigned short* __restrict__ outb, float* __restrict__ outf,
    unsigned short* __restrict__ outb2) {
  const int tid = threadIdx.x;
  const int cb = rb >> 6, rp = rb & 63;  // bid%8 == rp%8 -> A panel per-XCD
  const int row0 = rp * BM;

  const unsigned short* Bt;
  const int colg = (cb & 3) * 64;
  if (MODE == 0)
    Bt = (cb < 4) ? (wtT + (size_t)(cb * 64) * 768)
                  : (wlT + (size_t)((cb - 4) * 64) * 768);
  else
    Bt = (cb < 4) ? (wtT + (size_t)(cb * 64) * 768 + 512)
                  : (wlT + (size_t)((cb - 4) * 64) * 768 + 512);

  // staging map: A 128 rows x 4 segs of 8 f32; B 64 cols x 8 segs of 4 bf16
  const int arow = tid >> 2, akp = (tid & 3) * 8;
  const int bcol = tid >> 3, bkp = (tid & 7) * 4;
  const float* aptr = A + (size_t)(row0 + arow) * lda + akp;
  const unsigned short* bptr = Bt + (size_t)bcol * 768 + bkp;

  float4 ra0[2], ra1[2];
  uint2 rbv[2];
  auto LOADS = [&](int sl, int ks) {
    const float* ap = aptr + ks * BK;
    ra0[sl] = *(const float4*)ap;
    ra1[sl] = *(const float4*)(ap + 4);
    rbv[sl] = *(const uint2*)(bptr + ks * BK);
  };
  auto WRITE = [&](int sl, int buf) {
    unsigned short t[8] = {f2bf(ra0[sl].x), f2bf(ra0[sl].y), f2bf(ra0[sl].z),
                           f2bf(ra0[sl].w), f2bf(ra1[sl].x), f2bf(ra1[sl].y),
                           f2bf(ra1[sl].z), f2bf(ra1[sl].w)};
    *(uint4*)&As[buf][arow * 40 + akp] = *(const uint4*)t;
    *(uint2*)&Bs[buf][bcol * 40 + bkp] = rbv[sl];
  };

  const int w = tid >> 6, lane = tid & 63;
  const int lr = lane & 15, kg = lane >> 4;
  const int rbase = (w & 3) * 32;   // wave's 32-row group
  const int cbase = (w >> 2) * 32;  // wave's 32-col group

  f32x4 acc[2][2] = {{{0.f, 0.f, 0.f, 0.f}, {0.f, 0.f, 0.f, 0.f}},
                     {{0.f, 0.f, 0.f, 0.f}, {0.f, 0.f, 0.f, 0.f}}};

  LOADS(0, 0);
  if (KS > 1) LOADS(1, 1);
  WRITE(0, 0);
  __syncthreads();

#pragma unroll
  for (int ks = 0; ks < KS; ++ks) {
    if (ks + 2 < KS) LOADS(ks & 1, ks + 2);
    const int bf = ks & 1;
    bf16x8 a0 = *(const bf16x8*)&As[bf][(rbase + lr) * 40 + kg * 8];
    bf16x8 a1 = *(const bf16x8*)&As[bf][(rbase + 16 + lr) * 40 + kg * 8];
    bf16x8 b0 = *(const bf16x8*)&Bs[bf][(cbase + lr) * 40 + kg * 8];
    bf16x8 b1 = *(const bf16x8*)&Bs[bf][(cbase + 16 + lr) * 40 + kg * 8];
    acc[0][0] = __builtin_amdgcn_mfma_f32_16x16x32_bf16(a0, b0, acc[0][0], 0, 0, 0);
    acc[0][1] = __builtin_amdgcn_mfma_f32_16x16x32_bf16(a0, b1, acc[0][1], 0, 0, 0);
    acc[1][0] = __builtin_amdgcn_mfma_f32_16x16x32_bf16(a1, b0, acc[1][0], 0, 0, 0);
    acc[1][1] = __builtin_amdgcn_mfma_f32_16x16x32_bf16(a1, b1, acc[1][1], 0, 0, 0);
    if (ks + 1 < KS) WRITE((ks + 1) & 1, (ks + 1) & 1);
    __syncthreads();
  }

  // C/D layout: col=lane&15, row=(lane>>4)*4+r  [m89-verified]
#pragma unroll
  for (int m = 0; m < 2; ++m) {
#pragma unroll
    for (int f = 0; f < 2; ++f) {
      const int col = colg + cbase + f * 16 + lr;
#pragma unroll
      for (int r = 0; r < 4; ++r) {
        const int row = row0 + rbase + m * 16 + kg * 4 + r;
        float val = acc[m][f][r];
        if (MODE == 0) {
          if (cb < 4) {
            const float y = fminf((val + b_attn[col]) * ESCALE, ECLAMP);
            outb[(size_t)row * OUTF + col] = f2bf(__builtin_amdgcn_exp2f(y));
          } else {
            outf[(size_t)row * OUTF + col] = val + b_lin[col];
          }
        } else {
          if (cb < 4) {
            const float y = fminf(val * ESCALE, ECLAMP);
            outb[(size_t)row * OUTF + col] = f2bf(__builtin_amdgcn_exp2f(y));
          } else {
            outb2[(size_t)row * OUTF + col] = f2bf(val);
          }
        }
      }
    }
  }
}

// [0,512): x@[Wh|Wl1] -> xwe2,z1 ; [512,1024): enc@We -> ewe2, enc@Wl2 -> encWl2
__global__ __launch_bounds__(512) void gemmAB_kernel(
    const float* __restrict__ x, const float* __restrict__ enc,
    const unsigned short* __restrict__ wtT,
    const unsigned short* __restrict__ wlT,
    const float* __restrict__ b_attn, const float* __restrict__ b_lin,
    unsigned short* __restrict__ xwe2, float* __restrict__ z1,
    unsigned short* __restrict__ ewe2, unsigned short* __restrict__ encWl2) {
  __shared__ unsigned short As[2][BM * 40];
  __shared__ unsigned short Bs[2][BN * 40];
  if (blockIdx.x < 512)
    gemm_body<16, 0>(As, Bs, blockIdx.x, x, MODEL, wtT, wlT, b_attn, b_lin,
                     xwe2, z1, nullptr);
  else
    gemm_body<8, 1>(As, Bs, blockIdx.x - 512, enc, OUTF, wtT, wlT, nullptr,
                    nullptr, ewe2, nullptr, encWl2);
}

// ---- fused attention + banded final GEMM: 16 t-rows/block, 2 rows/wave ----
// weighted@Wl2 == Aband @ (enc@Wl2) by associativity; gemmAB precomputes
// encWl2. R15 FIX: the K=64 MFMA reads EwT k in [0,64) but staging only
// fills k<48 — k in [48,64) was uninitialized LDS, and 0*garbage = NaN.
// Zero that slice up front (512 aligned uint4 stores, 1/thread).
__global__ __launch_bounds__(512) void attn_gemmc_kernel(
    const unsigned short* __restrict__ xwe2,
    const unsigned short* __restrict__ ewe2,
    const unsigned short* __restrict__ encWl2, const float* __restrict__ v,
    const float* __restrict__ z1, float* __restrict__ out,
    float* __restrict__ a_out) {
  __shared__ unsigned short Ew[HALO * 256];  // 2^encwe halo (24.6 KB)
  __shared__ unsigned short EwT[256 * TS];   // (encWl2 halo)^T (36.9 KB)
  __shared__ unsigned short Ab[TB * TS];     // banded a (2.3 KB)

  const int tid = threadIdx.x;
  const int wv = tid >> 6, lane = tid & 63;
  const int rb = ((blockIdx.x & 7) << 6) | (blockIdx.x >> 3);  // XCD-grouped
  const int t0 = rb * TB;              // global bt of first row
  const int b = t0 >> 11;
  const int tloc = t0 & (T_DIM - 1);   // local t of first row
  const int g = lane >> 4, sl = lane & 15;

  // zero Ab (cols >=48 must be 0 for the K=64 MFMA; band written later)
  if (tid < TB * TS / 8) ((uint4*)Ab)[tid] = make_uint4(0, 0, 0, 0);
  // zero EwT k-slice [48,64) for all 256 cols (col*72+48 is 16B-aligned)
  {
    const int col = tid >> 1, off = 48 + (tid & 1) * 8;
    *(uint4*)&EwT[col * TS + off] = make_uint4(0, 0, 0, 0);
  }

  // stage Ew (2^ewe, OOB rows = 1.0) and EwT (encWl2 transposed, OOB = 0)
  for (int u = tid; u < HALO * 32; u += 512) {
    const int r = u >> 5, s = u & 31;  // 16B segs
    const int tg = tloc - WSZ + r;
    uint4 qe, qw;
    if ((unsigned)tg < T_DIM) {
      const size_t base = ((size_t)(b * T_DIM + tg)) << 8;
      qe = *(const uint4*)(ewe2 + base + s * 8);
      qw = *(const uint4*)(encWl2 + base + s * 8);
    } else {
      qe = make_uint4(0x3f803f80u, 0x3f803f80u, 0x3f803f80u, 0x3f803f80u);
      qw = make_uint4(0, 0, 0, 0);
    }
    *(uint4*)&Ew[r * 256 + s * 8] = qe;
    unsigned short tt[8];
    *(uint4*)tt = qw;
#pragma unroll
    for (int j = 0; j < 8; ++j) EwT[(s * 8 + j) * TS + r] = tt[j];
  }

  float vf[16];
  {
    const float4* vp = (const float4*)(v + sl * 16);
#pragma unroll
    for (int j = 0; j < 4; ++j) {
      float4 t4 = vp[j];
      vf[4 * j] = t4.x; vf[4 * j + 1] = t4.y;
      vf[4 * j + 2] = t4.z; vf[4 * j + 3] = t4.w;
    }
  }
  __syncthreads();

  const int lrow = wv * 2;               // wave's row pair
  const int bt0 = t0 + lrow, bt1 = bt0 + 1;

  float xe0[16], xe1[16];  // 2^xwh values for both rows' o-slice
  {
    const uint4* xp0 = (const uint4*)(xwe2 + ((size_t)bt0 << 8) + sl * 16);
    const uint4* xp1 = (const uint4*)(xwe2 + ((size_t)bt1 << 8) + sl * 16);
    uint4 q0 = xp0[0], q1 = xp0[1], q2 = xp1[0], q3 = xp1[1];
    unsigned int u0[8] = {q0.x, q0.y, q0.z, q0.w, q1.x, q1.y, q1.z, q1.w};
    unsigned int u1[8] = {q2.x, q2.y, q2.z, q2.w, q3.x, q3.y, q3.z, q3.w};
#pragma unroll
    for (int j = 0; j < 8; ++j) {
      xe0[2 * j] = bflo(u0[j]); xe0[2 * j + 1] = bfhi(u0[j]);
      xe1[2 * j] = bflo(u1[j]); xe1[2 * j + 1] = bfhi(u1[j]);
    }
  }

  // scores for BOTH rows: 9 chunks x 4 windows (16 lanes each)
  float s0 = 0.f, s1 = 0.f;  // lane w holds S(w) per row
#pragma unroll
  for (int c = 0; c < 9; ++c) {
    const int w_ = c * 4 + g;
    const int rl0 = min(lrow + w_, HALO - 1);      // clamp; invalid discarded
    const int rl1 = min(lrow + 1 + w_, HALO - 1);
    const uint4 a0q = *(const uint4*)&Ew[rl0 * 256 + sl * 16];
    const uint4 a1q = *(const uint4*)&Ew[rl0 * 256 + sl * 16 + 8];
    const uint4 b0q = *(const uint4*)&Ew[rl1 * 256 + sl * 16];
    const uint4 b1q = *(const uint4*)&Ew[rl1 * 256 + sl * 16 + 8];
    unsigned int e0[8] = {a0q.x, a0q.y, a0q.z, a0q.w, a1q.x, a1q.y, a1q.z, a1q.w};
    unsigned int e1[8] = {b0q.x, b0q.y, b0q.z, b0q.w, b1q.x, b1q.y, b1q.z, b1q.w};
    float acc0 = 0.f, acc1 = 0.f;
#pragma unroll
    for (int j = 0; j < 8; ++j) {
      const float v0 = vf[2 * j], v1 = vf[2 * j + 1];
      const float vsj = v0 + v1;
      {  // row0
        const float E0 = xe0[2 * j] * bflo(e0[j]);
        const float E1 = xe0[2 * j + 1] * bfhi(e0[j]);
        const float den = (E0 + 1.f) * (E1 + 1.f);
        float num = fmaf(v0, E1, vsj);
        num = fmaf(v1, E0, num);
        acc0 = fmaf(num, __builtin_amdgcn_rcpf(den), acc0);
      }
      {  // row1 (independent chain)
        const float E0 = xe1[2 * j] * bflo(e1[j]);
        const float E1 = xe1[2 * j + 1] * bfhi(e1[j]);
        const float den = (E0 + 1.f) * (E1 + 1.f);
        float num = fmaf(v0, E1, vsj);
        num = fmaf(v1, E0, num);
        acc1 = fmaf(num, __builtin_amdgcn_rcpf(den), acc1);
      }
    }
#pragma unroll
    for (int off = 1; off < 16; off <<= 1) {
      acc0 += __shfl_xor(acc0, off);
      acc1 += __shfl_xor(acc1, off);
    }
    const int src = (lane & 3) << 4;
    float c0v = __shfl(acc0, src), c1v = __shfl(acc1, src);
    if ((lane >> 2) == c) { s0 = c0v; s1 = c1v; }
  }

  // softmax without max-subtraction: score=-2S, |S|<=sum|v|~4.2 -> safe
  float p0 = (lane < WIN) ? __builtin_amdgcn_exp2f(-ESCALE * s0) : 0.f;
  float p1 = (lane < WIN) ? __builtin_amdgcn_exp2f(-ESCALE * s1) : 0.f;
  float q0 = p0, q1 = p1;
#pragma unroll
  for (int off = 1; off < 64; off <<= 1) {
    q0 += __shfl_xor(q0, off);
    q1 += __shfl_xor(q1, off);
  }
  const float a0v = p0 * __builtin_amdgcn_rcpf(q0);
  const float a1v = p1 * __builtin_amdgcn_rcpf(q1);
  if (lane < WIN) {
    a_out[(size_t)bt0 * WIN + lane] = a0v;
    a_out[(size_t)bt1 * WIN + lane] = a1v;
    // banded a-matrix: Ab[t][t+w] = a[t][w] (k in [0,48); rest stays 0).
    // OOB windows multiply zero EwT rows -> no masking needed.
    Ab[lrow * TS + lrow + lane] = f2bf(a0v);
    Ab[(lrow + 1) * TS + (lrow + 1) + lane] = f2bf(a1v);
  }
  __syncthreads();

  // banded GEMM: out[16,256] = sigmoid(z1 + Ab(16x64) @ EwT^T(64x256));
  // wave wv -> cols wv*32..+32; K=64 (cols 48..63 of Ab are zero)
  const int lr = lane & 15, kg = lane >> 4;
  f32x4 acc[2] = {{0.f, 0.f, 0.f, 0.f}, {0.f, 0.f, 0.f, 0.f}};
#pragma unroll
  for (int ks = 0; ks < 2; ++ks) {
    bf16x8 a = *(const bf16x8*)&Ab[lr * TS + ks * 32 + kg * 8];
#pragma unroll
    for (int f = 0; f < 2; ++f) {
      bf16x8 bb = *(const bf16x8*)&EwT[(wv * 32 + f * 16 + lr) * TS +
                                       ks * 32 + kg * 8];
      acc[f] = __builtin_amdgcn_mfma_f32_16x16x32_bf16(a, bb, acc[f], 0, 0, 0);
    }
  }
#pragma unroll
  for (int f = 0; f < 2; ++f) {
    const int col = wv * 32 + f * 16 + lr;
#pragma unroll
    for (int r = 0; r < 4; ++r) {
      const int row = t0 + kg * 4 + r;
      out[(size_t)row * OUTF + col] =
          fast_sigmoid(acc[f][r] + z1[(size_t)row * OUTF + col]);
    }
  }
}

extern "C" void kernel_launch(void* const* d_in, const int* in_sizes, int n_in,
                              void* d_out, int out_size, void* d_ws,
                              size_t ws_size, hipStream_t stream) {
  const float* x      = (const float*)d_in[0];  // [4,2048,512]
  const float* enc    = (const float*)d_in[1];  // [4,2048,256]
  const float* W_attn = (const float*)d_in[2];  // [768,256]
  const float* b_attn = (const float*)d_in[3];  // [256]
  const float* v      = (const float*)d_in[4];  // [256]
  const float* W_lin  = (const float*)d_in[5];  // [768,256]
  const float* b_lin  = (const float*)d_in[6];  // [256]

  float* out   = (float*)d_out;            // [BT,256]
  float* a_out = out + (size_t)BT * OUTF;  // [BT,33]

  unsigned short* wtT    = (unsigned short*)d_ws;     // [256][768] bf16
  unsigned short* wlT    = wtT + 768 * OUTF;          // [256][768] bf16
  unsigned short* xwe2   = wlT + 768 * OUTF;          // BT*256 bf16 (2^ vals)
  unsigned short* ewe2   = xwe2 + (size_t)BT * OUTF;  // BT*256 bf16 (2^ vals)
  unsigned short* encWl2 = ewe2 + (size_t)BT * OUTF;  // BT*256 bf16
  float*          z1     = (float*)(encWl2 + (size_t)BT * OUTF);  // BT*256 f32

  // transpose-cast both weights (1.5 MB)
  prepW_kernel<<<192, 256, 0, stream>>>(W_attn, W_lin, wtT, wlT);
  // x@[Wh|Wl1] -> xwe2,z1 ; enc@We -> ewe2 ; enc@Wl2 -> encWl2
  gemmAB_kernel<<<1024, 512, 0, stream>>>(x, enc, wtT, wlT, b_attn, b_lin,
                                          xwe2, z1, ewe2, encWl2);
  // fused attention + banded final GEMM (+sigmoid) -> out, a_out
  attn_gemmc_kernel<<<512, 512, 0, stream>>>(xwe2, ewe2, encWl2, v, z1,
                                             out, a_out);
}